// Round 6
// baseline (323.423 us; speedup 1.0000x reference)
//
#include <hip/hip_runtime.h>
#include <math.h>

#define BB 8192
#define DIN 1024
#define DZ 256
#define DH 256
#define DT 16
#define DREC 256

// d_out layout (floats): I_hat, z, h, z_hat, spatial, temporal, energy
#define OFF_IHAT 0
#define OFF_Z    (BB * DIN)
#define OFF_H    (OFF_Z + BB * DZ)
#define OFF_ZHAT (OFF_H + BB * DH)
#define OFF_SCAL (OFF_ZHAT + BB * DZ)

// bf16 weight pack offsets (u16 elements) in d_ws
#define WB_PM  0
#define WB_PL  262144
#define WB_Z2H 524288
#define WB_H2H 589824
#define WB_PRM 655360
#define WB_PRL 720896
#define WB_I2T 786432   // pre-scaled by 0.1
#define WB_VIP 802816   // stored as -relu(W)
#define WB_R1  806912
#define WB_R2  872448
#define WB_END 1134592

#define STRD 264    // 256-wide LDS row stride (u16)
#define ISTRD 1032  // 1024-wide LDS row stride (u16)

typedef unsigned short u16;
typedef __attribute__((ext_vector_type(8))) unsigned short u16x8;
typedef __attribute__((ext_vector_type(8))) __bf16 bf16x8;
typedef __attribute__((ext_vector_type(4))) float f32x4;

#define MFMA __builtin_amdgcn_mfma_f32_16x16x32_bf16

__device__ inline u16 f2bf(float f) {
  unsigned u = __builtin_bit_cast(unsigned, f);
  u += 0x7fff + ((u >> 16) & 1);
  return (u16)(u >> 16);
}
__device__ inline float bf2f(u16 v) {
  unsigned u = ((unsigned)v) << 16;
  return __builtin_bit_cast(float, u);
}
__device__ inline float softplus_stable(float y) {  // log(1+e^y)
  return (y > 20.f) ? y : log1pf(expf(y));
}
__device__ inline bf16x8 gf(const u16* p) {
  return __builtin_bit_cast(bf16x8, *(const u16x8*)p);
}
__device__ inline f32x4 fzero() { return (f32x4){0.f, 0.f, 0.f, 0.f}; }

__device__ inline float block_sum512(float v, float* rbuf) {
#pragma unroll
  for (int off = 32; off > 0; off >>= 1) v += __shfl_down(v, off, 64);
  __syncthreads();  // also protects rbuf reuse across calls
  if ((threadIdx.x & 63) == 0) rbuf[threadIdx.x >> 6] = v;
  __syncthreads();
  float s = 0.f;
#pragma unroll
  for (int i = 0; i < 8; ++i) s += rbuf[i];
  return s;
}

// 512 threads: stage 16 rows x 256 cols fp32 -> bf16 LDS (8 floats/thread)
__device__ inline void stage256(u16* lds, int lstrd,
                                const float* __restrict__ src, int row0,
                                int ld, int k0) {
  const int r = threadIdx.x & 15, cg = threadIdx.x >> 4;  // cg 0..31
  const float* p = src + (size_t)(row0 + r) * ld + k0 + cg * 8;
  float4 v0 = ((const float4*)p)[0];
  float4 v1 = ((const float4*)p)[1];
  float a[8] = {v0.x, v0.y, v0.z, v0.w, v1.x, v1.y, v1.z, v1.w};
  u16x8 o;
#pragma unroll
  for (int j = 0; j < 8; ++j) o[j] = f2bf(a[j]);
  *(u16x8*)(lds + r * lstrd + k0 + cg * 8) = o;
}

// ---------------------------------------------------------------------------
// k_cvtw: weights fp32 -> bf16 (0.1*Wi2t, -relu(Wvip2t) folded)
// ---------------------------------------------------------------------------
__global__ __launch_bounds__(256) void k_cvtw(
    const float* __restrict__ Wpm, const float* __restrict__ Wpl,
    const float* __restrict__ Wz2h, const float* __restrict__ Wh2h,
    const float* __restrict__ Wprm, const float* __restrict__ Wprl,
    const float* __restrict__ Wi2t, const float* __restrict__ Wv,
    const float* __restrict__ Wr1, const float* __restrict__ Wr2,
    u16* __restrict__ dst) {
  const int NT = WB_END / 8;
  for (int c = blockIdx.x * 256 + threadIdx.x; c < NT; c += gridDim.x * 256) {
    int f = c * 8;
    const float* src;
    float scale = 1.f;
    bool nrelu = false;
    if (f < WB_PL)        src = Wpm + f;
    else if (f < WB_Z2H)  src = Wpl + (f - WB_PL);
    else if (f < WB_H2H)  src = Wz2h + (f - WB_Z2H);
    else if (f < WB_PRM)  src = Wh2h + (f - WB_H2H);
    else if (f < WB_PRL)  src = Wprm + (f - WB_PRM);
    else if (f < WB_I2T)  src = Wprl + (f - WB_PRL);
    else if (f < WB_VIP)  { src = Wi2t + (f - WB_I2T); scale = 0.1f; }
    else if (f < WB_R1)   { src = Wv + (f - WB_VIP); nrelu = true; }
    else if (f < WB_R2)   src = Wr1 + (f - WB_R1);
    else                  src = Wr2 + (f - WB_R2);
    float4 v0 = *(const float4*)(src);
    float4 v1 = *(const float4*)(src + 4);
    float vals[8] = {v0.x, v0.y, v0.z, v0.w, v1.x, v1.y, v1.z, v1.w};
    u16x8 o;
#pragma unroll
    for (int j = 0; j < 8; ++j) {
      float x = vals[j];
      x = nrelu ? -fmaxf(x, 0.f) : x * scale;
      o[j] = f2bf(x);
    }
    *(u16x8*)(dst + f) = o;
  }
}

// ---------------------------------------------------------------------------
// k_mega: entire model for a 16-row strip. Grid 512 x 512 threads (8 waves).
// Wave w owns cols [w*32,(w+1)*32) in N=256 phases, [w*128,(w+1)*128) in rec2.
// ---------------------------------------------------------------------------
__global__ __launch_bounds__(512, 4) void k_mega(
    const float* __restrict__ I_t, const float* __restrict__ h_m_1,
    const float* __restrict__ z_m_1, const float* __restrict__ theta_m_1,
    const float* __restrict__ eps_z, const float* __restrict__ eps_zhat,
    const float* __restrict__ W_t2z, const u16* __restrict__ Wb,
    float* __restrict__ ihat, float* __restrict__ zout,
    float* __restrict__ hout, float* __restrict__ zhatout,
    float* __restrict__ scal) {
  __shared__ __align__(16) u16 I_lds[16 * ISTRD];   // 33 KB, persistent
  __shared__ __align__(16) u16 A_lds[16 * STRD];    // h, later z
  __shared__ __align__(16) u16 Z_lds[16 * STRD];    // z_m_1
  __shared__ __align__(16) u16 B_lds[16 * STRD];    // sigma, later r1
  __shared__ float th_s[16 * 17];
  __shared__ float wt_s[256 * 17];
  __shared__ float rbuf[8];

  const int tid = threadIdx.x, lane = tid & 63, w = tid >> 6;
  const int frow = lane & 15, fq = lane >> 4;
  const int row0 = blockIdx.x * 16;
  const int cb = w * 32;  // this wave's 32-col slice in N=256 phases

  const u16* Wpm  = Wb + WB_PM;
  const u16* Wpl  = Wb + WB_PL;
  const u16* Wz2h = Wb + WB_Z2H;
  const u16* Wh2h = Wb + WB_H2H;
  const u16* Wprm = Wb + WB_PRM;
  const u16* Wprl = Wb + WB_PRL;
  const u16* Wi2t = Wb + WB_I2T;
  const u16* Wv   = Wb + WB_VIP;
  const u16* Wr1  = Wb + WB_R1;
  const u16* Wr2  = Wb + WB_R2;

  // ---- stage EVERYTHING up front (max loads in flight, one barrier) -------
  stage256(A_lds, STRD, h_m_1, row0, DH, 0);
  stage256(Z_lds, STRD, z_m_1, row0, DZ, 0);
#pragma unroll
  for (int c = 0; c < 4; ++c) stage256(I_lds, ISTRD, I_t, row0, DIN, c * 256);
  {  // 10*relu(W_t2z) -> wt_s  (256 rows x 16)
    int n = tid >> 1, j0 = (tid & 1) * 8;
    const float* q = W_t2z + n * 16 + j0;
    float4 a0 = ((const float4*)q)[0], a1 = ((const float4*)q)[1];
    float v[8] = {a0.x, a0.y, a0.z, a0.w, a1.x, a1.y, a1.z, a1.w};
#pragma unroll
    for (int j = 0; j < 8; ++j) wt_s[n * 17 + j0 + j] = 10.f * fmaxf(v[j], 0.f);
  }
  __syncthreads();

  // ---- phase 1: A = h (K=256): h-rec, mu_p, sigma_p -----------------------
  f32x4 ah[2], am[2], as_[2];
#pragma unroll
  for (int i = 0; i < 2; ++i) { ah[i] = fzero(); am[i] = fzero(); as_[i] = fzero(); }
  {
    const u16* pA = A_lds + frow * STRD + fq * 8;
    const u16* pH = Wh2h + (size_t)(cb + frow) * DH + fq * 8;
    const u16* pM = Wprm + (size_t)(cb + frow) * DH + fq * 8;
    const u16* pS = Wprl + (size_t)(cb + frow) * DH + fq * 8;
#pragma unroll 4
    for (int ks = 0; ks < 8; ++ks) {
      bf16x8 a = gf(pA + ks * 32);
#pragma unroll
      for (int ni = 0; ni < 2; ++ni) {
        ah[ni]  = MFMA(a, gf(pH + ni * 16 * DH + ks * 32), ah[ni], 0, 0, 0);
        am[ni]  = MFMA(a, gf(pM + ni * 16 * DH + ks * 32), am[ni], 0, 0, 0);
        as_[ni] = MFMA(a, gf(pS + ni * 16 * DH + ks * 32), as_[ni], 0, 0, 0);
      }
    }
  }
  // ---- phase 2: A = z_m_1 (K=256): h += zm1@Wz2h --------------------------
  {
    const u16* pA = Z_lds + frow * STRD + fq * 8;
    const u16* pZ = Wz2h + (size_t)(cb + frow) * DZ + fq * 8;
#pragma unroll 4
    for (int ks = 0; ks < 8; ++ks) {
      bf16x8 a = gf(pA + ks * 32);
#pragma unroll
      for (int ni = 0; ni < 2; ++ni)
        ah[ni] = MFMA(a, gf(pZ + ni * 16 * DZ + ks * 32), ah[ni], 0, 0, 0);
    }
  }
  // ---- epilogue 1: h, z_hat out; sigma -> B_lds; zh kept in regs ----------
  f32x4 zh[2];
#pragma unroll
  for (int ni = 0; ni < 2; ++ni)
#pragma unroll
    for (int r = 0; r < 4; ++r) {
      int m = row0 + fq * 4 + r;
      int n = cb + ni * 16 + frow;
      hout[(size_t)m * DH + n] = fmaxf(ah[ni][r], 0.f);
      float sig = softplus_stable(1.2f * as_[ni][r]) * (1.f / 1.2f);
      float mu = fmaxf(am[ni][r], 0.f);
      float z = mu + eps_zhat[(size_t)m * DZ + n] * sig;
      zh[ni][r] = z;
      zhatout[(size_t)m * DZ + n] = z;
      B_lds[(fq * 4 + r) * STRD + n] = f2bf(sig);
    }
  __syncthreads();  // sigma visible

  // ---- phase 3: theta sigma-part (redundant per wave) ---------------------
  f32x4 acct = fzero();
  {
    const u16* pA = B_lds + frow * STRD + fq * 8;
    const u16* pV = Wv + (size_t)frow * DZ + fq * 8;
#pragma unroll 4
    for (int ks = 0; ks < 8; ++ks)
      acct = MFMA(gf(pA + ks * 32), gf(pV + ks * 32), acct, 0, 0, 0);
  }
  // ---- phase 4: A = I (K=1024, LDS-resident): mu_q, sigma_q, theta --------
  f32x4 accm[2], accs[2];
#pragma unroll
  for (int i = 0; i < 2; ++i) { accm[i] = fzero(); accs[i] = fzero(); }
  {
    const u16* pA = I_lds + frow * ISTRD + fq * 8;
    const u16* pM = Wpm + (size_t)(cb + frow) * DIN + fq * 8;
    const u16* pS = Wpl + (size_t)(cb + frow) * DIN + fq * 8;
    const u16* pT = Wi2t + (size_t)frow * DIN + fq * 8;
#pragma unroll 1
    for (int c = 0; c < 4; ++c) {
      int kb = c * 256;
#pragma unroll 4
      for (int ks = 0; ks < 8; ++ks) {
        bf16x8 a = gf(pA + kb + ks * 32);
#pragma unroll
        for (int ni = 0; ni < 2; ++ni) {
          accm[ni] = MFMA(a, gf(pM + ni * 16 * DIN + kb + ks * 32), accm[ni], 0, 0, 0);
          accs[ni] = MFMA(a, gf(pS + ni * 16 * DIN + kb + ks * 32), accs[ni], 0, 0, 0);
        }
        acct = MFMA(a, gf(pT + kb + ks * 32), acct, 0, 0, 0);
      }
    }
  }
  // ---- theta finalize (wave 0 writes) -------------------------------------
  if (w == 0) {
#pragma unroll
    for (int r = 0; r < 4; ++r) {
      int lr = fq * 4 + r;
      float th = 0.5f * theta_m_1[(size_t)(row0 + lr) * DT + frow] + acct[r];
      th_s[lr * 17 + frow] = 0.002f * softplus_stable(0.5f * th);
    }
  }
  __syncthreads();

  // ---- z epilogue + temporal/energy ---------------------------------------
  float tsum = 0.f, esum = 0.f;
#pragma unroll
  for (int ni = 0; ni < 2; ++ni)
#pragma unroll
    for (int r = 0; r < 4; ++r) {
      int lr = fq * 4 + r;
      int ln = cb + ni * 16 + frow;
      int m = row0 + lr;
      float mu = fmaxf(accm[ni][r], 0.f);
      float sq = fmaxf(accs[ni][r], 0.f);
      float raw = mu + eps_z[(size_t)m * DZ + ln] * sq;
      raw = fminf(fmaxf(raw, 0.f), 1.f);
      float thr = 0.f;
#pragma unroll
      for (int j = 0; j < 16; ++j)
        thr = fmaf(th_s[lr * 17 + j], wt_s[ln * 17 + j], thr);
      float zz = fmaxf(raw - thr, 0.f);
      zout[(size_t)m * DZ + ln] = zz;
      A_lds[lr * STRD + ln] = f2bf(zz);  // phase-1 reads long done
      float d = zz - zh[ni][r];
      tsum += d * d;
      esum += zz;
    }
  float t = block_sum512(tsum, rbuf);
  if (tid == 0) atomicAdd(scal + 1, t * (1.f / ((float)BB * DZ)));
  float e = block_sum512(esum, rbuf);
  if (tid == 0) atomicAdd(scal + 2, e * (1.f / ((float)BB * DZ)));
  // block_sum's internal barriers ensure z (A_lds) visible to all waves

  // ---- rec1: r1 = z @ Wr1^T -----------------------------------------------
  f32x4 ar[2] = {fzero(), fzero()};
  {
    const u16* pA = A_lds + frow * STRD + fq * 8;
    const u16* pR = Wr1 + (size_t)(cb + frow) * DZ + fq * 8;
#pragma unroll 4
    for (int ks = 0; ks < 8; ++ks) {
      bf16x8 a = gf(pA + ks * 32);
#pragma unroll
      for (int ni = 0; ni < 2; ++ni)
        ar[ni] = MFMA(a, gf(pR + ni * 16 * DZ + ks * 32), ar[ni], 0, 0, 0);
    }
  }
#pragma unroll
  for (int ni = 0; ni < 2; ++ni)
#pragma unroll
    for (int r = 0; r < 4; ++r)
      B_lds[(fq * 4 + r) * STRD + cb + ni * 16 + frow] = f2bf(ar[ni][r]);
  __syncthreads();

  // ---- rec2: I_hat = sigmoid(r1 @ Wr2^T), spatial loss --------------------
  f32x4 ai[8];
#pragma unroll
  for (int i = 0; i < 8; ++i) ai[i] = fzero();
  {
    const u16* pA = B_lds + frow * STRD + fq * 8;
    const u16* pR = Wr2 + (size_t)(w * 128 + frow) * DREC + fq * 8;
#pragma unroll 2
    for (int ks = 0; ks < 8; ++ks) {
      bf16x8 a = gf(pA + ks * 32);
#pragma unroll
      for (int ni = 0; ni < 8; ++ni)
        ai[ni] = MFMA(a, gf(pR + ni * 16 * DREC + ks * 32), ai[ni], 0, 0, 0);
    }
  }
  float lsum = 0.f;
#pragma unroll
  for (int ni = 0; ni < 8; ++ni)
#pragma unroll
    for (int r = 0; r < 4; ++r) {
      int lr = fq * 4 + r;
      int m = row0 + lr;
      int n = w * 128 + ni * 16 + frow;
      float ih = 1.f / (1.f + expf(-ai[ni][r]));
      ihat[(size_t)m * DIN + n] = ih;
      float d = bf2f(I_lds[lr * ISTRD + n]) - ih;
      lsum += d * d;
    }
  float s = block_sum512(lsum, rbuf);
  if (tid == 0) atomicAdd(scal + 0, s * (1.f / ((float)BB * DIN)));
}

// ---------------------------------------------------------------------------
extern "C" void kernel_launch(void* const* d_in, const int* in_sizes, int n_in,
                              void* d_out, int out_size, void* d_ws,
                              size_t ws_size, hipStream_t stream) {
  const float* I_t       = (const float*)d_in[0];
  const float* h_m_1     = (const float*)d_in[1];
  const float* z_m_1     = (const float*)d_in[2];
  const float* theta_m_1 = (const float*)d_in[3];
  const float* eps_z     = (const float*)d_in[4];
  const float* eps_zhat  = (const float*)d_in[5];
  const float* W_post_mu = (const float*)d_in[6];
  const float* W_post_lv = (const float*)d_in[7];
  const float* W_z2h     = (const float*)d_in[8];
  const float* W_h2h     = (const float*)d_in[9];
  const float* W_prior_mu= (const float*)d_in[10];
  const float* W_prior_lv= (const float*)d_in[11];
  const float* W_i2t     = (const float*)d_in[12];
  const float* W_vip2t   = (const float*)d_in[13];
  const float* W_t2z     = (const float*)d_in[14];
  const float* W_rec1    = (const float*)d_in[15];
  const float* W_rec2    = (const float*)d_in[16];

  float* out = (float*)d_out;
  float* ihat = out + OFF_IHAT;
  float* zout = out + OFF_Z;
  float* hout = out + OFF_H;
  float* zhat = out + OFF_ZHAT;
  float* scal = out + OFF_SCAL;

  u16* Wb = (u16*)d_ws;

  hipMemsetAsync(scal, 0, 3 * sizeof(float), stream);

  k_cvtw<<<512, 256, 0, stream>>>(W_post_mu, W_post_lv, W_z2h, W_h2h,
                                  W_prior_mu, W_prior_lv, W_i2t, W_vip2t,
                                  W_rec1, W_rec2, Wb);
  k_mega<<<BB / 16, 512, 0, stream>>>(I_t, h_m_1, z_m_1, theta_m_1, eps_z,
                                      eps_zhat, W_t2z, Wb, ihat, zout, hout,
                                      zhat, scal);
}

// Round 7
// 273.716 us; speedup vs baseline: 1.1816x; 1.1816x over previous
//
#include <hip/hip_runtime.h>
#include <math.h>

#define BB 8192
#define DIN 1024
#define DZ 256
#define DH 256
#define DT 16
#define DREC 256

// d_out layout (floats): I_hat, z, h, z_hat, spatial, temporal, energy
#define OFF_IHAT 0
#define OFF_Z    (BB * DIN)
#define OFF_H    (OFF_Z + BB * DZ)
#define OFF_ZHAT (OFF_H + BB * DH)
#define OFF_SCAL (OFF_ZHAT + BB * DZ)

// ---- workspace layout (u16 element offsets) -------------------------------
#define WS_HBF   0
#define WS_ZM1   2097152
#define WS_W     4194304
#define W_PM  (WS_W + 0)
#define W_PL  (W_PM + 262144)
#define W_Z2H (W_PL + 262144)
#define W_H2H (W_Z2H + 65536)
#define W_PRM (W_H2H + 65536)
#define W_PRL (W_PRM + 65536)
#define W_I2T (W_PRL + 65536)      // pre-scaled by 0.1
#define W_VIP (W_I2T + 16384)      // stored as -relu(W)
#define W_R1  (W_VIP + 4096)
#define W_R2  (W_R1 + 65536)
#define WS_ENDW  (W_R2 + 262144)
#define WS_SIGMA WS_ENDW
#define WS_ZBF   (WS_SIGMA + 2097152)
#define WS_R1BF  (WS_ZBF + 2097152)

typedef unsigned short u16;
typedef __attribute__((ext_vector_type(8))) unsigned short u16x8;
typedef __attribute__((ext_vector_type(8))) __bf16 bf16x8;
typedef __attribute__((ext_vector_type(4))) float f32x4;

#define MFMA __builtin_amdgcn_mfma_f32_16x16x32_bf16

__device__ inline u16 f2bf(float f) {
  unsigned u = __builtin_bit_cast(unsigned, f);
  u += 0x7fff + ((u >> 16) & 1);
  return (u16)(u >> 16);
}
__device__ inline float softplus_stable(float y) {  // log(1+e^y)
  return (y > 20.f) ? y : log1pf(expf(y));
}
__device__ inline bf16x8 gf(const u16* p) {
  return __builtin_bit_cast(bf16x8, *(const u16x8*)p);
}
__device__ inline f32x4 fzero() { return (f32x4){0.f, 0.f, 0.f, 0.f}; }

__device__ inline float block_sum256(float v, float* rbuf) {
#pragma unroll
  for (int off = 32; off > 0; off >>= 1) v += __shfl_down(v, off, 64);
  __syncthreads();
  if ((threadIdx.x & 63) == 0) rbuf[threadIdx.x >> 6] = v;
  __syncthreads();
  return rbuf[0] + rbuf[1] + rbuf[2] + rbuf[3];
}

// ---- async DMA staging: 64-row x 64-col bf16 tile, XOR-swizzled -----------
// LDS layout: row r occupies u16 [r*64, r*64+64); 16B group g stores the
// logical group (g ^ (r&7)). DMA: wave w stages rows w*16..w*16+15.
__device__ inline void dma64(u16* tile, const u16* __restrict__ gsrc,
                             int row0, int ldk, int k0) {
  const int lane = threadIdx.x & 63, w = threadIdx.x >> 6;
#pragma unroll
  for (int c = 0; c < 2; ++c) {
    int rb = w * 16 + c * 8;
    int r = rb + (lane >> 3);
    int gl = (lane & 7) ^ (r & 7);
    const u16* src = gsrc + (size_t)(row0 + r) * ldk + k0 + gl * 8;
    u16* dst = tile + rb * 64;  // wave-uniform base; HW adds lane*16B
    __builtin_amdgcn_global_load_lds(
        (const __attribute__((address_space(1))) unsigned int*)(const void*)src,
        (__attribute__((address_space(3))) unsigned int*)(void*)dst, 16, 0, 0);
  }
}
// 16-row x 64-col tile (theta B): waves 0,1 stage 8 rows each.
__device__ inline void dma16(u16* tile, const u16* __restrict__ gsrc,
                             int ldk, int k0) {
  const int lane = threadIdx.x & 63, w = threadIdx.x >> 6;
  if (w < 2) {
    int rb = w * 8;
    int r = rb + (lane >> 3);
    int gl = (lane & 7) ^ (r & 7);
    const u16* src = gsrc + (size_t)r * ldk + k0 + gl * 8;
    u16* dst = tile + rb * 64;
    __builtin_amdgcn_global_load_lds(
        (const __attribute__((address_space(1))) unsigned int*)(const void*)src,
        (__attribute__((address_space(3))) unsigned int*)(void*)dst, 16, 0, 0);
  }
}
// swizzled ds_read of one 16B fragment: logical group gl of row r
__device__ inline bf16x8 rd(const u16* tile, int r, int gl) {
  return gf(tile + r * 64 + ((gl ^ (r & 7)) * 8));
}

// ---------------------------------------------------------------------------
// k_cvt: fp32 -> bf16 for all GEMM operands, with folded scalings.
// ---------------------------------------------------------------------------
__global__ __launch_bounds__(256) void k_cvt(
    const float* __restrict__ I_t, const float* __restrict__ h_m_1,
    const float* __restrict__ z_m_1, const float* __restrict__ Wpm,
    const float* __restrict__ Wpl, const float* __restrict__ Wz2h,
    const float* __restrict__ Wh2h, const float* __restrict__ Wprm,
    const float* __restrict__ Wprl, const float* __restrict__ Wi2t,
    const float* __restrict__ Wv, const float* __restrict__ Wr1,
    const float* __restrict__ Wr2, u16* __restrict__ dstI,
    u16* __restrict__ dstW) {
  const int S1 = 8388608, S2 = 10485760, S3 = 12582912, S4 = 12845056,
            S5 = 13107200, S6 = 13172736, S7 = 13238272, S8 = 13303808,
            S9 = 13369344, S10 = 13385728, S11 = 13389824, S12 = 13455360,
            S13 = 13717504;
  int nchunk = S13 / 8;
  for (int c = blockIdx.x * 256 + threadIdx.x; c < nchunk;
       c += gridDim.x * 256) {
    int f = c * 8;
    const float* src;
    float scale = 1.f;
    bool nrelu = false;
    u16* dst;
    if (f < S1) {
      src = I_t + f;
      dst = dstI + f;
    } else {
      dst = dstW + (f - S1);
      if (f < S2)       src = h_m_1 + (f - S1);
      else if (f < S3)  src = z_m_1 + (f - S2);
      else if (f < S4)  src = Wpm + (f - S3);
      else if (f < S5)  src = Wpl + (f - S4);
      else if (f < S6)  src = Wz2h + (f - S5);
      else if (f < S7)  src = Wh2h + (f - S6);
      else if (f < S8)  src = Wprm + (f - S7);
      else if (f < S9)  src = Wprl + (f - S8);
      else if (f < S10) { src = Wi2t + (f - S9);  scale = 0.1f; }
      else if (f < S11) { src = Wv + (f - S10);   nrelu = true; }
      else if (f < S12) src = Wr1 + (f - S11);
      else              src = Wr2 + (f - S12);
    }
    float4 v0 = *(const float4*)(src);
    float4 v1 = *(const float4*)(src + 4);
    float vals[8] = {v0.x, v0.y, v0.z, v0.w, v1.x, v1.y, v1.z, v1.w};
    u16x8 o;
#pragma unroll
    for (int j = 0; j < 8; ++j) {
      float x = vals[j];
      x = nrelu ? -fmaxf(x, 0.f) : x * scale;
      o[j] = f2bf(x);
    }
    *(u16x8*)(dst) = o;
  }
}

// ---------------------------------------------------------------------------
// k_hp: h = relu(zm1@Wz2h^T + h@Wh2h^T); sigma_p = softplus_b(h@Wprl^T)/1.2;
//       z_hat = relu(h@Wprm^T) + eps_zhat*sigma_p; sigma -> bf16 ws.
// 64x64 tile, m97-style DMA staging. Grid (4,128)=512.
// ---------------------------------------------------------------------------
__global__ __launch_bounds__(256, 4) void k_hp(
    const u16* __restrict__ h_bf, const u16* __restrict__ zm1,
    const u16* __restrict__ Wh2h, const u16* __restrict__ Wprm,
    const u16* __restrict__ Wprl, const u16* __restrict__ Wz2h,
    const float* __restrict__ eps_zhat, float* __restrict__ h_out,
    float* __restrict__ zhat_out, u16* __restrict__ sigma_bf) {
  __shared__ __align__(16) u16 As[64 * 64], B0s[64 * 64], B1s[64 * 64],
      B2s[64 * 64];
  const int tid = threadIdx.x, lane = tid & 63, w = tid >> 6;
  const int frow = lane & 15, fq = lane >> 4;
  const int col0 = blockIdx.x * 64, row0 = blockIdx.y * 64;
  f32x4 ah[4], am[4], as_[4];
#pragma unroll
  for (int i = 0; i < 4; ++i) { ah[i] = fzero(); am[i] = fzero(); as_[i] = fzero(); }

  // pass 1: A = h (K=256): Wh2h, Wprm, Wprl
  for (int k0 = 0; k0 < DH; k0 += 64) {
    __syncthreads();
    dma64(As, h_bf, row0, DH, k0);
    dma64(B0s, Wh2h, col0, DH, k0);
    dma64(B1s, Wprm, col0, DH, k0);
    dma64(B2s, Wprl, col0, DH, k0);
    __syncthreads();
#pragma unroll
    for (int ks = 0; ks < 2; ++ks) {
      bf16x8 a = rd(As, w * 16 + frow, ks * 4 + fq);
#pragma unroll
      for (int ni = 0; ni < 4; ++ni) {
        ah[ni]  = MFMA(a, rd(B0s, ni * 16 + frow, ks * 4 + fq), ah[ni], 0, 0, 0);
        am[ni]  = MFMA(a, rd(B1s, ni * 16 + frow, ks * 4 + fq), am[ni], 0, 0, 0);
        as_[ni] = MFMA(a, rd(B2s, ni * 16 + frow, ks * 4 + fq), as_[ni], 0, 0, 0);
      }
    }
  }
  // pass 2: A = z_m_1 (K=256): Wz2h into ah
  for (int k0 = 0; k0 < DZ; k0 += 64) {
    __syncthreads();
    dma64(As, zm1, row0, DZ, k0);
    dma64(B0s, Wz2h, col0, DZ, k0);
    __syncthreads();
#pragma unroll
    for (int ks = 0; ks < 2; ++ks) {
      bf16x8 a = rd(As, w * 16 + frow, ks * 4 + fq);
#pragma unroll
      for (int ni = 0; ni < 4; ++ni)
        ah[ni] = MFMA(a, rd(B0s, ni * 16 + frow, ks * 4 + fq), ah[ni], 0, 0, 0);
    }
  }
#pragma unroll
  for (int ni = 0; ni < 4; ++ni)
#pragma unroll
    for (int r = 0; r < 4; ++r) {
      int m = row0 + w * 16 + fq * 4 + r;
      int n = col0 + ni * 16 + frow;
      h_out[(size_t)m * DH + n] = fmaxf(ah[ni][r], 0.f);
      float sig = softplus_stable(1.2f * as_[ni][r]) * (1.f / 1.2f);
      float mu = fmaxf(am[ni][r], 0.f);
      zhat_out[(size_t)m * DZ + n] = mu + eps_zhat[(size_t)m * DZ + n] * sig;
      sigma_bf[(size_t)m * DZ + n] = f2bf(sig);
    }
}

// ---------------------------------------------------------------------------
// k_post: mu_q/sigma_q (K=1024) + theta riding same A tiles + sigma@(-reluWv)
// + fused z epilogue with temporal/energy losses. 64x64 tile, grid (4,128).
// ---------------------------------------------------------------------------
__global__ __launch_bounds__(256, 4) void k_post(
    const u16* __restrict__ I_bf, const u16* __restrict__ Wpm,
    const u16* __restrict__ Wpl, const u16* __restrict__ Wi2t,
    const u16* __restrict__ Wv, const u16* __restrict__ sigma_bf,
    const float* __restrict__ theta_m_1, const float* __restrict__ W_t2z,
    const float* __restrict__ eps_z, const float* __restrict__ zhat,
    float* __restrict__ z_out, u16* __restrict__ z_bf,
    float* __restrict__ scal) {
  __shared__ __align__(16) u16 As[64 * 64], B0s[64 * 64], B1s[64 * 64],
      Bts[16 * 64];
  __shared__ float th_s[64 * 17];
  __shared__ float wt_s[64 * 17];
  __shared__ float rbuf[4];
  const int tid = threadIdx.x, lane = tid & 63, w = tid >> 6;
  const int frow = lane & 15, fq = lane >> 4;
  const int col0 = blockIdx.x * 64, row0 = blockIdx.y * 64;
  f32x4 accm[4], accs[4], acct = fzero();
#pragma unroll
  for (int i = 0; i < 4; ++i) { accm[i] = fzero(); accs[i] = fzero(); }

  // main loop: A = I (K=1024)
  for (int k0 = 0; k0 < DIN; k0 += 64) {
    __syncthreads();
    dma64(As, I_bf, row0, DIN, k0);
    dma64(B0s, Wpm, col0, DIN, k0);
    dma64(B1s, Wpl, col0, DIN, k0);
    dma16(Bts, Wi2t, DIN, k0);
    __syncthreads();
#pragma unroll
    for (int ks = 0; ks < 2; ++ks) {
      bf16x8 a = rd(As, w * 16 + frow, ks * 4 + fq);
#pragma unroll
      for (int ni = 0; ni < 4; ++ni) {
        accm[ni] = MFMA(a, rd(B0s, ni * 16 + frow, ks * 4 + fq), accm[ni], 0, 0, 0);
        accs[ni] = MFMA(a, rd(B1s, ni * 16 + frow, ks * 4 + fq), accs[ni], 0, 0, 0);
      }
      acct = MFMA(a, rd(Bts, frow, ks * 4 + fq), acct, 0, 0, 0);
    }
  }
  // theta sigma-part: A = sigma (K=256), B = -relu(Wv)
  for (int k0 = 0; k0 < DZ; k0 += 64) {
    __syncthreads();
    dma64(As, sigma_bf, row0, DZ, k0);
    dma16(Bts, Wv, DZ, k0);
    __syncthreads();
#pragma unroll
    for (int ks = 0; ks < 2; ++ks)
      acct = MFMA(rd(As, w * 16 + frow, ks * 4 + fq),
                  rd(Bts, frow, ks * 4 + fq), acct, 0, 0, 0);
  }
  // theta finalize (each wave owns its 16 rows) + threshold weights
  __syncthreads();
#pragma unroll
  for (int r = 0; r < 4; ++r) {
    int lr = w * 16 + fq * 4 + r;
    float th = 0.5f * theta_m_1[(size_t)(row0 + lr) * DT + frow] + acct[r];
    th_s[lr * 17 + frow] = 0.002f * softplus_stable(0.5f * th);
  }
  for (int idx = tid; idx < 64 * 16; idx += 256) {
    int n = idx >> 4, j = idx & 15;
    wt_s[n * 17 + j] = 10.f * fmaxf(W_t2z[(col0 + n) * DT + j], 0.f);
  }
  __syncthreads();
  // z epilogue + temporal/energy
  float tsum = 0.f, esum = 0.f;
#pragma unroll
  for (int ni = 0; ni < 4; ++ni)
#pragma unroll
    for (int r = 0; r < 4; ++r) {
      int lr = w * 16 + fq * 4 + r;
      int ln = ni * 16 + frow;
      int m = row0 + lr;
      int n = col0 + ln;
      float mu = fmaxf(accm[ni][r], 0.f);
      float sq = fmaxf(accs[ni][r], 0.f);
      float raw = mu + eps_z[(size_t)m * DZ + n] * sq;
      raw = fminf(fmaxf(raw, 0.f), 1.f);
      float thr = 0.f;
#pragma unroll
      for (int j = 0; j < 16; ++j)
        thr = fmaf(th_s[lr * 17 + j], wt_s[ln * 17 + j], thr);
      float zz = fmaxf(raw - thr, 0.f);
      z_out[(size_t)m * DZ + n] = zz;
      z_bf[(size_t)m * DZ + n] = f2bf(zz);
      float d = zz - zhat[(size_t)m * DZ + n];
      tsum += d * d;
      esum += zz;
    }
  float t = block_sum256(tsum, rbuf);
  if (tid == 0) atomicAdd(scal + 1, t * (1.f / ((float)BB * DZ)));
  float e = block_sum256(esum, rbuf);
  if (tid == 0) atomicAdd(scal + 2, e * (1.f / ((float)BB * DZ)));
}

// ---------------------------------------------------------------------------
// k_rec1: r1 = z @ Wr1^T -> bf16 ws. 64x64 tile, grid (4,128).
// ---------------------------------------------------------------------------
__global__ __launch_bounds__(256, 4) void k_rec1(const u16* __restrict__ z_bf,
                                                 const u16* __restrict__ Wr1,
                                                 u16* __restrict__ r1_bf) {
  __shared__ __align__(16) u16 As[64 * 64], B0s[64 * 64];
  const int tid = threadIdx.x, lane = tid & 63, w = tid >> 6;
  const int frow = lane & 15, fq = lane >> 4;
  const int col0 = blockIdx.x * 64, row0 = blockIdx.y * 64;
  f32x4 acc[4] = {fzero(), fzero(), fzero(), fzero()};
  for (int k0 = 0; k0 < DZ; k0 += 64) {
    __syncthreads();
    dma64(As, z_bf, row0, DZ, k0);
    dma64(B0s, Wr1, col0, DZ, k0);
    __syncthreads();
#pragma unroll
    for (int ks = 0; ks < 2; ++ks) {
      bf16x8 a = rd(As, w * 16 + frow, ks * 4 + fq);
#pragma unroll
      for (int ni = 0; ni < 4; ++ni)
        acc[ni] = MFMA(a, rd(B0s, ni * 16 + frow, ks * 4 + fq), acc[ni], 0, 0, 0);
    }
  }
#pragma unroll
  for (int ni = 0; ni < 4; ++ni)
#pragma unroll
    for (int r = 0; r < 4; ++r) {
      int m = row0 + w * 16 + fq * 4 + r;
      int n = col0 + ni * 16 + frow;
      r1_bf[(size_t)m * DREC + n] = f2bf(acc[ni][r]);
    }
}

// ---------------------------------------------------------------------------
// k_rec2: I_hat = sigmoid(r1 @ Wr2^T) + fused spatial loss.
// 64x64 tile, grid (16,128)=2048.
// ---------------------------------------------------------------------------
__global__ __launch_bounds__(256, 4) void k_rec2(const u16* __restrict__ r1_bf,
                                                 const u16* __restrict__ Wr2,
                                                 const float* __restrict__ I_t,
                                                 float* __restrict__ ihat_out,
                                                 float* __restrict__ scal) {
  __shared__ __align__(16) u16 As[64 * 64], B0s[64 * 64];
  __shared__ float rbuf[4];
  const int tid = threadIdx.x, lane = tid & 63, w = tid >> 6;
  const int frow = lane & 15, fq = lane >> 4;
  const int col0 = blockIdx.x * 64, row0 = blockIdx.y * 64;
  f32x4 acc[4] = {fzero(), fzero(), fzero(), fzero()};
  for (int k0 = 0; k0 < DREC; k0 += 64) {
    __syncthreads();
    dma64(As, r1_bf, row0, DREC, k0);
    dma64(B0s, Wr2, col0, DREC, k0);
    __syncthreads();
#pragma unroll
    for (int ks = 0; ks < 2; ++ks) {
      bf16x8 a = rd(As, w * 16 + frow, ks * 4 + fq);
#pragma unroll
      for (int ni = 0; ni < 4; ++ni)
        acc[ni] = MFMA(a, rd(B0s, ni * 16 + frow, ks * 4 + fq), acc[ni], 0, 0, 0);
    }
  }
  float lsum = 0.f;
#pragma unroll
  for (int ni = 0; ni < 4; ++ni)
#pragma unroll
    for (int r = 0; r < 4; ++r) {
      int m = row0 + w * 16 + fq * 4 + r;
      int n = col0 + ni * 16 + frow;
      float ih = 1.f / (1.f + expf(-acc[ni][r]));
      ihat_out[(size_t)m * DIN + n] = ih;
      float d = I_t[(size_t)m * DIN + n] - ih;
      lsum += d * d;
    }
  float s = block_sum256(lsum, rbuf);
  if (tid == 0) atomicAdd(scal + 0, s * (1.f / ((float)BB * DIN)));
}

// ---------------------------------------------------------------------------
extern "C" void kernel_launch(void* const* d_in, const int* in_sizes, int n_in,
                              void* d_out, int out_size, void* d_ws,
                              size_t ws_size, hipStream_t stream) {
  const float* I_t       = (const float*)d_in[0];
  const float* h_m_1     = (const float*)d_in[1];
  const float* z_m_1     = (const float*)d_in[2];
  const float* theta_m_1 = (const float*)d_in[3];
  const float* eps_z     = (const float*)d_in[4];
  const float* eps_zhat  = (const float*)d_in[5];
  const float* W_post_mu = (const float*)d_in[6];
  const float* W_post_lv = (const float*)d_in[7];
  const float* W_z2h     = (const float*)d_in[8];
  const float* W_h2h     = (const float*)d_in[9];
  const float* W_prior_mu= (const float*)d_in[10];
  const float* W_prior_lv= (const float*)d_in[11];
  const float* W_i2t     = (const float*)d_in[12];
  const float* W_vip2t   = (const float*)d_in[13];
  const float* W_t2z     = (const float*)d_in[14];
  const float* W_rec1    = (const float*)d_in[15];
  const float* W_rec2    = (const float*)d_in[16];

  float* out = (float*)d_out;
  float* ihat = out + OFF_IHAT;
  float* zout = out + OFF_Z;
  float* hout = out + OFF_H;
  float* zhat = out + OFF_ZHAT;
  float* scal = out + OFF_SCAL;

  u16* ws_u = (u16*)d_ws;
  u16* I_bf = (u16*)ihat;  // scratch inside d_out, dead before k_rec2 writes
  u16* h_bf = ws_u + WS_HBF;
  u16* zm1_bf = ws_u + WS_ZM1;
  u16* sigma_bf = ws_u + WS_SIGMA;
  u16* z_bf = ws_u + WS_ZBF;
  u16* r1_bf = ws_u + WS_R1BF;

  hipMemsetAsync(scal, 0, 3 * sizeof(float), stream);

  k_cvt<<<2048, 256, 0, stream>>>(I_t, h_m_1, z_m_1, W_post_mu, W_post_lv,
                                  W_z2h, W_h2h, W_prior_mu, W_prior_lv, W_i2t,
                                  W_vip2t, W_rec1, W_rec2, I_bf, ws_u + WS_HBF);

  dim3 gz(DZ / 64, BB / 64);    // 4 x 128 = 512
  dim3 gi(DIN / 64, BB / 64);   // 16 x 128 = 2048

  k_hp<<<gz, 256, 0, stream>>>(h_bf, zm1_bf, ws_u + W_H2H, ws_u + W_PRM,
                               ws_u + W_PRL, ws_u + W_Z2H, eps_zhat, hout,
                               zhat, sigma_bf);
  k_post<<<gz, 256, 0, stream>>>(I_bf, ws_u + W_PM, ws_u + W_PL, ws_u + W_I2T,
                                 ws_u + W_VIP, sigma_bf, theta_m_1, W_t2z,
                                 eps_z, zhat, zout, z_bf, scal);
  k_rec1<<<gz, 256, 0, stream>>>(z_bf, ws_u + W_R1, r1_bf);
  k_rec2<<<gi, 256, 0, stream>>>(r1_bf, ws_u + W_R2, I_t, ihat, scal);
}

// Round 8
// 245.684 us; speedup vs baseline: 1.3164x; 1.1141x over previous
//
#include <hip/hip_runtime.h>
#include <math.h>

#define BB 8192
#define DIN 1024
#define DZ 256
#define DH 256
#define DT 16
#define DREC 256

// d_out layout (floats): I_hat, z, h, z_hat, spatial, temporal, energy
#define OFF_IHAT 0
#define OFF_Z    (BB * DIN)
#define OFF_H    (OFF_Z + BB * DZ)
#define OFF_ZHAT (OFF_H + BB * DH)
#define OFF_SCAL (OFF_ZHAT + BB * DZ)

// ---- workspace layout (u16 element offsets) -------------------------------
#define WS_HBF   0
#define WS_ZM1   2097152
#define WS_W     4194304
#define W_PM  (WS_W + 0)
#define W_PL  (W_PM + 262144)
#define W_Z2H (W_PL + 262144)
#define W_H2H (W_Z2H + 65536)
#define W_PRM (W_H2H + 65536)
#define W_PRL (W_PRM + 65536)
#define W_I2T (W_PRL + 65536)      // pre-scaled by 0.1
#define W_VIP (W_I2T + 16384)      // stored as -relu(W)
#define W_R1  (W_VIP + 4096)
#define W_R2  (W_R1 + 65536)
#define WS_ENDW  (W_R2 + 262144)
#define WS_SIGMA WS_ENDW
#define WS_ZBF   (WS_SIGMA + 2097152)
#define WS_R1BF  (WS_ZBF + 2097152)

typedef unsigned short u16;
typedef __attribute__((ext_vector_type(8))) unsigned short u16x8;
typedef __attribute__((ext_vector_type(8))) __bf16 bf16x8;
typedef __attribute__((ext_vector_type(4))) float f32x4;

#define MFMA __builtin_amdgcn_mfma_f32_16x16x32_bf16

__device__ inline u16 f2bf(float f) {
  unsigned u = __builtin_bit_cast(unsigned, f);
  u += 0x7fff + ((u >> 16) & 1);
  return (u16)(u >> 16);
}
__device__ inline float softplus_stable(float y) {  // log(1+e^y)
  return (y > 20.f) ? y : log1pf(expf(y));
}
__device__ inline bf16x8 gf(const u16* p) {
  return __builtin_bit_cast(bf16x8, *(const u16x8*)p);
}
__device__ inline f32x4 fzero() { return (f32x4){0.f, 0.f, 0.f, 0.f}; }

__device__ inline float block_sum256(float v, float* rbuf) {
#pragma unroll
  for (int off = 32; off > 0; off >>= 1) v += __shfl_down(v, off, 64);
  __syncthreads();
  if ((threadIdx.x & 63) == 0) rbuf[threadIdx.x >> 6] = v;
  __syncthreads();
  return rbuf[0] + rbuf[1] + rbuf[2] + rbuf[3];
}

// XCD-aware decode: 4 col-blocks of a row-band share an XCD (id % 8).
__device__ inline void decode4(int id, int rows, int& row0, int& col0) {
  int xcd = id & 7, t = id >> 3;
  col0 = (t & 3) * 64;
  row0 = ((t >> 2) * 8 + xcd) * rows;
}

// ---- async DMA staging (XOR-swizzled LDS, global_load_lds width=16) -------
// 32-row x 64-col: wave w stages rows w*8..w*8+7.
__device__ inline void dmaA32(u16* tile, const u16* __restrict__ gsrc,
                              int row0, int ldk, int k0) {
  const int lane = threadIdx.x & 63, w = threadIdx.x >> 6;
  int rb = w * 8;
  int r = rb + (lane >> 3);
  int gl = (lane & 7) ^ (r & 7);
  const u16* src = gsrc + (size_t)(row0 + r) * ldk + k0 + gl * 8;
  u16* dst = tile + rb * 64;
  __builtin_amdgcn_global_load_lds(
      (const __attribute__((address_space(1))) unsigned int*)(const void*)src,
      (__attribute__((address_space(3))) unsigned int*)(void*)dst, 16, 0, 0);
}
// 64-row x 64-col: wave w stages rows w*16..w*16+15 (2 calls).
__device__ inline void dmaB64(u16* tile, const u16* __restrict__ gsrc,
                              int row0, int ldk, int k0) {
  const int lane = threadIdx.x & 63, w = threadIdx.x >> 6;
#pragma unroll
  for (int c = 0; c < 2; ++c) {
    int rb = w * 16 + c * 8;
    int r = rb + (lane >> 3);
    int gl = (lane & 7) ^ (r & 7);
    const u16* src = gsrc + (size_t)(row0 + r) * ldk + k0 + gl * 8;
    u16* dst = tile + rb * 64;
    __builtin_amdgcn_global_load_lds(
        (const __attribute__((address_space(1))) unsigned int*)(const void*)src,
        (__attribute__((address_space(3))) unsigned int*)(void*)dst, 16, 0, 0);
  }
}
// 16-row x 64-col (theta B): waves 0,1 stage 8 rows each.
__device__ inline void dma16(u16* tile, const u16* __restrict__ gsrc, int ldk,
                             int k0) {
  const int lane = threadIdx.x & 63, w = threadIdx.x >> 6;
  if (w < 2) {
    int rb = w * 8;
    int r = rb + (lane >> 3);
    int gl = (lane & 7) ^ (r & 7);
    const u16* src = gsrc + (size_t)r * ldk + k0 + gl * 8;
    u16* dst = tile + rb * 64;
    __builtin_amdgcn_global_load_lds(
        (const __attribute__((address_space(1))) unsigned int*)(const void*)src,
        (__attribute__((address_space(3))) unsigned int*)(void*)dst, 16, 0, 0);
  }
}
__device__ inline bf16x8 rd(const u16* tile, int r, int gl) {
  return gf(tile + r * 64 + ((gl ^ (r & 7)) * 8));
}

// ---------------------------------------------------------------------------
// k_cvt: fp32 -> bf16 for all GEMM operands, with folded scalings.
// ---------------------------------------------------------------------------
__global__ __launch_bounds__(256) void k_cvt(
    const float* __restrict__ I_t, const float* __restrict__ h_m_1,
    const float* __restrict__ z_m_1, const float* __restrict__ Wpm,
    const float* __restrict__ Wpl, const float* __restrict__ Wz2h,
    const float* __restrict__ Wh2h, const float* __restrict__ Wprm,
    const float* __restrict__ Wprl, const float* __restrict__ Wi2t,
    const float* __restrict__ Wv, const float* __restrict__ Wr1,
    const float* __restrict__ Wr2, u16* __restrict__ dstI,
    u16* __restrict__ dstW) {
  const int S1 = 8388608, S2 = 10485760, S3 = 12582912, S4 = 12845056,
            S5 = 13107200, S6 = 13172736, S7 = 13238272, S8 = 13303808,
            S9 = 13369344, S10 = 13385728, S11 = 13389824, S12 = 13455360,
            S13 = 13717504;
  int nchunk = S13 / 8;
  for (int c = blockIdx.x * 256 + threadIdx.x; c < nchunk;
       c += gridDim.x * 256) {
    int f = c * 8;
    const float* src;
    float scale = 1.f;
    bool nrelu = false;
    u16* dst;
    if (f < S1) {
      src = I_t + f;
      dst = dstI + f;
    } else {
      dst = dstW + (f - S1);
      if (f < S2)       src = h_m_1 + (f - S1);
      else if (f < S3)  src = z_m_1 + (f - S2);
      else if (f < S4)  src = Wpm + (f - S3);
      else if (f < S5)  src = Wpl + (f - S4);
      else if (f < S6)  src = Wz2h + (f - S5);
      else if (f < S7)  src = Wh2h + (f - S6);
      else if (f < S8)  src = Wprm + (f - S7);
      else if (f < S9)  src = Wprl + (f - S8);
      else if (f < S10) { src = Wi2t + (f - S9);  scale = 0.1f; }
      else if (f < S11) { src = Wv + (f - S10);   nrelu = true; }
      else if (f < S12) src = Wr1 + (f - S11);
      else              src = Wr2 + (f - S12);
    }
    float4 v0 = *(const float4*)(src);
    float4 v1 = *(const float4*)(src + 4);
    float vals[8] = {v0.x, v0.y, v0.z, v0.w, v1.x, v1.y, v1.z, v1.w};
    u16x8 o;
#pragma unroll
    for (int j = 0; j < 8; ++j) {
      float x = vals[j];
      x = nrelu ? -fmaxf(x, 0.f) : x * scale;
      o[j] = f2bf(x);
    }
    *(u16x8*)(dst) = o;
  }
}

// ---------------------------------------------------------------------------
// k_hp: h = relu(zm1@Wz2h^T + h@Wh2h^T); sigma_p = softplus_b(h@Wprl^T)/1.2;
//       z_hat = relu(h@Wprm^T) + eps_zhat*sigma_p; sigma -> bf16 ws.
// 32x64 tile, grid 1024 (XCD-swizzled), transposed contiguous epilogue.
// ---------------------------------------------------------------------------
__global__ __launch_bounds__(256, 4) void k_hp(
    const u16* __restrict__ h_bf, const u16* __restrict__ zm1,
    const u16* __restrict__ Wh2h, const u16* __restrict__ Wprm,
    const u16* __restrict__ Wprl, const u16* __restrict__ Wz2h,
    const float* __restrict__ eps_zhat, float* __restrict__ h_out,
    float* __restrict__ zhat_out, u16* __restrict__ sigma_bf) {
  __shared__ __align__(16) u16 smem[2048 + 3 * 4096];  // 28 KB
  u16* As = smem;
  u16* B0s = smem + 2048;
  u16* B1s = B0s + 4096;
  u16* B2s = B1s + 4096;
  const int tid = threadIdx.x, lane = tid & 63, w = tid >> 6;
  const int frow = lane & 15, fq = lane >> 4;
  const int wr = w & 1, wc = w >> 1;
  int row0, col0;
  decode4(blockIdx.x, 32, row0, col0);

  f32x4 ah[2], am[2], as_[2];
#pragma unroll
  for (int i = 0; i < 2; ++i) { ah[i] = fzero(); am[i] = fzero(); as_[i] = fzero(); }

  // pass 1: A = h (K=256): Wh2h, Wprm, Wprl
  for (int k0 = 0; k0 < DH; k0 += 64) {
    __syncthreads();
    dmaA32(As, h_bf, row0, DH, k0);
    dmaB64(B0s, Wh2h, col0, DH, k0);
    dmaB64(B1s, Wprm, col0, DH, k0);
    dmaB64(B2s, Wprl, col0, DH, k0);
    __syncthreads();
#pragma unroll
    for (int ks = 0; ks < 2; ++ks) {
      bf16x8 a = rd(As, wr * 16 + frow, ks * 4 + fq);
#pragma unroll
      for (int ni = 0; ni < 2; ++ni) {
        int br = wc * 32 + ni * 16 + frow;
        ah[ni]  = MFMA(a, rd(B0s, br, ks * 4 + fq), ah[ni], 0, 0, 0);
        am[ni]  = MFMA(a, rd(B1s, br, ks * 4 + fq), am[ni], 0, 0, 0);
        as_[ni] = MFMA(a, rd(B2s, br, ks * 4 + fq), as_[ni], 0, 0, 0);
      }
    }
  }
  // pass 2: A = z_m_1 (K=256): Wz2h into ah
  for (int k0 = 0; k0 < DZ; k0 += 64) {
    __syncthreads();
    dmaA32(As, zm1, row0, DZ, k0);
    dmaB64(B0s, Wz2h, col0, DZ, k0);
    __syncthreads();
#pragma unroll
    for (int ks = 0; ks < 2; ++ks) {
      bf16x8 a = rd(As, wr * 16 + frow, ks * 4 + fq);
#pragma unroll
      for (int ni = 0; ni < 2; ++ni)
        ah[ni] = MFMA(a, rd(B0s, wc * 32 + ni * 16 + frow, ks * 4 + fq),
                      ah[ni], 0, 0, 0);
    }
  }
  // scattered epilogue -> LDS tiles (stride 66)
  __syncthreads();
  float* ht = (float*)smem;             // 32x66
  float* mt = (float*)(smem + 4224);    // 32x66
  float* st = (float*)(smem + 8448);    // 32x66
#pragma unroll
  for (int ni = 0; ni < 2; ++ni)
#pragma unroll
    for (int r = 0; r < 4; ++r) {
      int lr = wr * 16 + fq * 4 + r;
      int ln = wc * 32 + ni * 16 + frow;
      ht[lr * 66 + ln] = fmaxf(ah[ni][r], 0.f);
      mt[lr * 66 + ln] = fmaxf(am[ni][r], 0.f);
      st[lr * 66 + ln] = softplus_stable(1.2f * as_[ni][r]) * (1.f / 1.2f);
    }
  __syncthreads();
  // linear contiguous writes: thread -> row tid>>3, cols (tid&7)*8..+8
  {
    int lr2 = tid >> 3, c0 = (tid & 7) * 8;
    int m2 = row0 + lr2;
    float h8[8], mu8[8], sg8[8];
#pragma unroll
    for (int j = 0; j < 8; ++j) {
      h8[j] = ht[lr2 * 66 + c0 + j];
      mu8[j] = mt[lr2 * 66 + c0 + j];
      sg8[j] = st[lr2 * 66 + c0 + j];
    }
    float* hp = h_out + (size_t)m2 * DH + col0 + c0;
    *(float4*)hp = make_float4(h8[0], h8[1], h8[2], h8[3]);
    *(float4*)(hp + 4) = make_float4(h8[4], h8[5], h8[6], h8[7]);
    const float* ep = eps_zhat + (size_t)m2 * DZ + col0 + c0;
    float4 e0 = ((const float4*)ep)[0], e1 = ((const float4*)ep)[1];
    float e8[8] = {e0.x, e0.y, e0.z, e0.w, e1.x, e1.y, e1.z, e1.w};
    float zh8[8];
    u16x8 sb;
#pragma unroll
    for (int j = 0; j < 8; ++j) {
      zh8[j] = mu8[j] + e8[j] * sg8[j];
      sb[j] = f2bf(sg8[j]);
    }
    float* zp = zhat_out + (size_t)m2 * DZ + col0 + c0;
    *(float4*)zp = make_float4(zh8[0], zh8[1], zh8[2], zh8[3]);
    *(float4*)(zp + 4) = make_float4(zh8[4], zh8[5], zh8[6], zh8[7]);
    *(u16x8*)(sigma_bf + (size_t)m2 * DZ + col0 + c0) = sb;
  }
}

// ---------------------------------------------------------------------------
// k_post: mu_q/sigma_q (K=1024) + theta riding same A tiles + sigma@(-reluWv)
// + fused z epilogue (transposed writes) with temporal/energy losses.
// 32x64 tile, grid 1024 (XCD-swizzled).
// ---------------------------------------------------------------------------
__global__ __launch_bounds__(256, 4) void k_post(
    const u16* __restrict__ I_bf, const u16* __restrict__ Wpm,
    const u16* __restrict__ Wpl, const u16* __restrict__ Wi2t,
    const u16* __restrict__ Wv, const u16* __restrict__ sigma_bf,
    const float* __restrict__ theta_m_1, const float* __restrict__ W_t2z,
    const float* __restrict__ eps_z, const float* __restrict__ zhat,
    float* __restrict__ z_out, u16* __restrict__ z_bf,
    float* __restrict__ scal) {
  __shared__ __align__(16) u16 smem[2048 + 4096 + 4096 + 1024];
  u16* As = smem;
  u16* B0s = smem + 2048;
  u16* B1s = B0s + 4096;
  u16* Bts = B1s + 4096;
  __shared__ float th_s[32 * 17];
  __shared__ float wt_s[64 * 17];
  __shared__ float rbuf[4];
  const int tid = threadIdx.x, lane = tid & 63, w = tid >> 6;
  const int frow = lane & 15, fq = lane >> 4;
  const int wr = w & 1, wc = w >> 1;
  int row0, col0;
  decode4(blockIdx.x, 32, row0, col0);

  f32x4 accm[2], accs[2], acct = fzero();
#pragma unroll
  for (int i = 0; i < 2; ++i) { accm[i] = fzero(); accs[i] = fzero(); }

  // main loop: A = I (K=1024)
  for (int k0 = 0; k0 < DIN; k0 += 64) {
    __syncthreads();
    dmaA32(As, I_bf, row0, DIN, k0);
    dmaB64(B0s, Wpm, col0, DIN, k0);
    dmaB64(B1s, Wpl, col0, DIN, k0);
    dma16(Bts, Wi2t, DIN, k0);
    __syncthreads();
#pragma unroll
    for (int ks = 0; ks < 2; ++ks) {
      bf16x8 a = rd(As, wr * 16 + frow, ks * 4 + fq);
#pragma unroll
      for (int ni = 0; ni < 2; ++ni) {
        int br = wc * 32 + ni * 16 + frow;
        accm[ni] = MFMA(a, rd(B0s, br, ks * 4 + fq), accm[ni], 0, 0, 0);
        accs[ni] = MFMA(a, rd(B1s, br, ks * 4 + fq), accs[ni], 0, 0, 0);
      }
      acct = MFMA(a, rd(Bts, frow, ks * 4 + fq), acct, 0, 0, 0);
    }
  }
  // theta sigma-part: A = sigma (K=256), B = -relu(Wv)
  for (int k0 = 0; k0 < DZ; k0 += 64) {
    __syncthreads();
    dmaA32(As, sigma_bf, row0, DZ, k0);
    dma16(Bts, Wv, DZ, k0);
    __syncthreads();
#pragma unroll
    for (int ks = 0; ks < 2; ++ks)
      acct = MFMA(rd(As, wr * 16 + frow, ks * 4 + fq),
                  rd(Bts, frow, ks * 4 + fq), acct, 0, 0, 0);
  }
  // theta finalize (waves with wc==0 own rows) + threshold weights
  __syncthreads();
  if (wc == 0) {
#pragma unroll
    for (int r = 0; r < 4; ++r) {
      int lr = wr * 16 + fq * 4 + r;
      float th = 0.5f * theta_m_1[(size_t)(row0 + lr) * DT + frow] + acct[r];
      th_s[lr * 17 + frow] = 0.002f * softplus_stable(0.5f * th);
    }
  }
  for (int idx = tid; idx < 64 * 16; idx += 256) {
    int n = idx >> 4, j = idx & 15;
    wt_s[n * 17 + j] = 10.f * fmaxf(W_t2z[(col0 + n) * DT + j], 0.f);
  }
  __syncthreads();
  // scattered z-compute -> zt tile
  float* zt = (float*)B0s;  // 32x66, B0s/B1s dead
#pragma unroll
  for (int ni = 0; ni < 2; ++ni)
#pragma unroll
    for (int r = 0; r < 4; ++r) {
      int lr = wr * 16 + fq * 4 + r;
      int ln = wc * 32 + ni * 16 + frow;
      int m = row0 + lr;
      float mu = fmaxf(accm[ni][r], 0.f);
      float sq = fmaxf(accs[ni][r], 0.f);
      float raw = mu + eps_z[(size_t)m * DZ + col0 + ln] * sq;
      raw = fminf(fmaxf(raw, 0.f), 1.f);
      float thr = 0.f;
#pragma unroll
      for (int j = 0; j < 16; ++j)
        thr = fmaf(th_s[lr * 17 + j], wt_s[ln * 17 + j], thr);
      zt[lr * 66 + ln] = fmaxf(raw - thr, 0.f);
    }
  __syncthreads();
  // linear phase: contiguous z_out/z_bf writes + zhat read + reductions
  float tsum = 0.f, esum = 0.f;
  {
    int lr2 = tid >> 3, c0 = (tid & 7) * 8;
    int m2 = row0 + lr2;
    float z8[8];
#pragma unroll
    for (int j = 0; j < 8; ++j) z8[j] = zt[lr2 * 66 + c0 + j];
    float* zp = z_out + (size_t)m2 * DZ + col0 + c0;
    *(float4*)zp = make_float4(z8[0], z8[1], z8[2], z8[3]);
    *(float4*)(zp + 4) = make_float4(z8[4], z8[5], z8[6], z8[7]);
    u16x8 zb;
#pragma unroll
    for (int j = 0; j < 8; ++j) zb[j] = f2bf(z8[j]);
    *(u16x8*)(z_bf + (size_t)m2 * DZ + col0 + c0) = zb;
    const float* zhp = zhat + (size_t)m2 * DZ + col0 + c0;
    float4 h0 = ((const float4*)zhp)[0], h1 = ((const float4*)zhp)[1];
    float zh8[8] = {h0.x, h0.y, h0.z, h0.w, h1.x, h1.y, h1.z, h1.w};
#pragma unroll
    for (int j = 0; j < 8; ++j) {
      float d = z8[j] - zh8[j];
      tsum += d * d;
      esum += z8[j];
    }
  }
  float t = block_sum256(tsum, rbuf);
  if (tid == 0) atomicAdd(scal + 1, t * (1.f / ((float)BB * DZ)));
  float e = block_sum256(esum, rbuf);
  if (tid == 0) atomicAdd(scal + 2, e * (1.f / ((float)BB * DZ)));
}

// ---------------------------------------------------------------------------
// k_rec1: r1 = z @ Wr1^T -> bf16 ws. 32x64 tile, grid 1024 (XCD-swizzled).
// ---------------------------------------------------------------------------
__global__ __launch_bounds__(256, 4) void k_rec1(const u16* __restrict__ z_bf,
                                                 const u16* __restrict__ Wr1,
                                                 u16* __restrict__ r1_bf) {
  __shared__ __align__(16) u16 smem[2048 + 4096];
  u16* As = smem;
  u16* B0s = smem + 2048;
  const int tid = threadIdx.x, lane = tid & 63, w = tid >> 6;
  const int frow = lane & 15, fq = lane >> 4;
  const int wr = w & 1, wc = w >> 1;
  int row0, col0;
  decode4(blockIdx.x, 32, row0, col0);
  f32x4 acc[2] = {fzero(), fzero()};
  for (int k0 = 0; k0 < DZ; k0 += 64) {
    __syncthreads();
    dmaA32(As, z_bf, row0, DZ, k0);
    dmaB64(B0s, Wr1, col0, DZ, k0);
    __syncthreads();
#pragma unroll
    for (int ks = 0; ks < 2; ++ks) {
      bf16x8 a = rd(As, wr * 16 + frow, ks * 4 + fq);
#pragma unroll
      for (int ni = 0; ni < 2; ++ni)
        acc[ni] = MFMA(a, rd(B0s, wc * 32 + ni * 16 + frow, ks * 4 + fq),
                       acc[ni], 0, 0, 0);
    }
  }
  __syncthreads();
  float* rt = (float*)smem;  // 32x66
#pragma unroll
  for (int ni = 0; ni < 2; ++ni)
#pragma unroll
    for (int r = 0; r < 4; ++r) {
      int lr = wr * 16 + fq * 4 + r;
      int ln = wc * 32 + ni * 16 + frow;
      rt[lr * 66 + ln] = acc[ni][r];
    }
  __syncthreads();
  {
    int lr2 = tid >> 3, c0 = (tid & 7) * 8;
    int m2 = row0 + lr2;
    u16x8 rb;
#pragma unroll
    for (int j = 0; j < 8; ++j) rb[j] = f2bf(rt[lr2 * 66 + c0 + j]);
    *(u16x8*)(r1_bf + (size_t)m2 * DREC + col0 + c0) = rb;
  }
}

// ---------------------------------------------------------------------------
// k_rec2: I_hat = sigmoid(r1 @ Wr2^T) + fused spatial loss.
// 64x64 tile, grid 2048 (XCD-swizzled), 2-pass transposed epilogue.
// ---------------------------------------------------------------------------
__global__ __launch_bounds__(256, 4) void k_rec2(const u16* __restrict__ r1_bf,
                                                 const u16* __restrict__ Wr2,
                                                 const float* __restrict__ I_t,
                                                 float* __restrict__ ihat_out,
                                                 float* __restrict__ scal) {
  __shared__ __align__(16) u16 smem[4096 + 4096];
  u16* As = smem;
  u16* B0s = smem + 4096;
  __shared__ float rbuf[4];
  const int tid = threadIdx.x, lane = tid & 63, w = tid >> 6;
  const int frow = lane & 15, fq = lane >> 4;
  int row0, col0;
  {
    int id = blockIdx.x;
    int xcd = id & 7, t = id >> 3;
    col0 = (t & 15) * 64;
    row0 = ((t >> 4) * 8 + xcd) * 64;
  }
  f32x4 acc[4] = {fzero(), fzero(), fzero(), fzero()};
  for (int k0 = 0; k0 < DREC; k0 += 64) {
    __syncthreads();
    dmaB64(As, r1_bf, row0, DREC, k0);
    dmaB64(B0s, Wr2, col0, DREC, k0);
    __syncthreads();
#pragma unroll
    for (int ks = 0; ks < 2; ++ks) {
      bf16x8 a = rd(As, w * 16 + frow, ks * 4 + fq);
#pragma unroll
      for (int ni = 0; ni < 4; ++ni)
        acc[ni] = MFMA(a, rd(B0s, ni * 16 + frow, ks * 4 + fq), acc[ni], 0, 0, 0);
    }
  }
  float lsum = 0.f;
  float* it = (float*)smem;  // 32x66, reused per pass
#pragma unroll 1
  for (int p = 0; p < 2; ++p) {
    __syncthreads();
    if ((w >> 1) == p) {
#pragma unroll
      for (int ni = 0; ni < 4; ++ni)
#pragma unroll
        for (int r = 0; r < 4; ++r) {
          int lrl = (w & 1) * 16 + fq * 4 + r;
          int ln = ni * 16 + frow;
          it[lrl * 66 + ln] = 1.f / (1.f + expf(-acc[ni][r]));
        }
    }
    __syncthreads();
    int lr2 = tid >> 3, c0 = (tid & 7) * 8;
    int m2 = row0 + p * 32 + lr2;
    float i8[8];
#pragma unroll
    for (int j = 0; j < 8; ++j) i8[j] = it[lr2 * 66 + c0 + j];
    float* op = ihat_out + (size_t)m2 * DIN + col0 + c0;
    *(float4*)op = make_float4(i8[0], i8[1], i8[2], i8[3]);
    *(float4*)(op + 4) = make_float4(i8[4], i8[5], i8[6], i8[7]);
    const float* ip = I_t + (size_t)m2 * DIN + col0 + c0;
    float4 a0 = ((const float4*)ip)[0], a1 = ((const float4*)ip)[1];
    float t8[8] = {a0.x, a0.y, a0.z, a0.w, a1.x, a1.y, a1.z, a1.w};
#pragma unroll
    for (int j = 0; j < 8; ++j) {
      float d = t8[j] - i8[j];
      lsum += d * d;
    }
  }
  float s = block_sum256(lsum, rbuf);
  if (tid == 0) atomicAdd(scal + 0, s * (1.f / ((float)BB * DIN)));
}

// ---------------------------------------------------------------------------
extern "C" void kernel_launch(void* const* d_in, const int* in_sizes, int n_in,
                              void* d_out, int out_size, void* d_ws,
                              size_t ws_size, hipStream_t stream) {
  const float* I_t       = (const float*)d_in[0];
  const float* h_m_1     = (const float*)d_in[1];
  const float* z_m_1     = (const float*)d_in[2];
  const float* theta_m_1 = (const float*)d_in[3];
  const float* eps_z     = (const float*)d_in[4];
  const float* eps_zhat  = (const float*)d_in[5];
  const float* W_post_mu = (const float*)d_in[6];
  const float* W_post_lv = (const float*)d_in[7];
  const float* W_z2h     = (const float*)d_in[8];
  const float* W_h2h     = (const float*)d_in[9];
  const float* W_prior_mu= (const float*)d_in[10];
  const float* W_prior_lv= (const float*)d_in[11];
  const float* W_i2t     = (const float*)d_in[12];
  const float* W_vip2t   = (const float*)d_in[13];
  const float* W_t2z     = (const float*)d_in[14];
  const float* W_rec1    = (const float*)d_in[15];
  const float* W_rec2    = (const float*)d_in[16];

  float* out = (float*)d_out;
  float* ihat = out + OFF_IHAT;
  float* zout = out + OFF_Z;
  float* hout = out + OFF_H;
  float* zhat = out + OFF_ZHAT;
  float* scal = out + OFF_SCAL;

  u16* ws_u = (u16*)d_ws;
  u16* I_bf = (u16*)ihat;  // scratch inside d_out, dead before k_rec2 writes
  u16* h_bf = ws_u + WS_HBF;
  u16* zm1_bf = ws_u + WS_ZM1;
  u16* sigma_bf = ws_u + WS_SIGMA;
  u16* z_bf = ws_u + WS_ZBF;
  u16* r1_bf = ws_u + WS_R1BF;

  hipMemsetAsync(scal, 0, 3 * sizeof(float), stream);

  k_cvt<<<2048, 256, 0, stream>>>(I_t, h_m_1, z_m_1, W_post_mu, W_post_lv,
                                  W_z2h, W_h2h, W_prior_mu, W_prior_lv, W_i2t,
                                  W_vip2t, W_rec1, W_rec2, I_bf, ws_u + WS_HBF);

  k_hp<<<1024, 256, 0, stream>>>(h_bf, zm1_bf, ws_u + W_H2H, ws_u + W_PRM,
                                 ws_u + W_PRL, ws_u + W_Z2H, eps_zhat, hout,
                                 zhat, sigma_bf);
  k_post<<<1024, 256, 0, stream>>>(I_bf, ws_u + W_PM, ws_u + W_PL,
                                   ws_u + W_I2T, ws_u + W_VIP, sigma_bf,
                                   theta_m_1, W_t2z, eps_z, zhat, zout, z_bf,
                                   scal);
  k_rec1<<<1024, 256, 0, stream>>>(z_bf, ws_u + W_R1, r1_bf);
  k_rec2<<<2048, 256, 0, stream>>>(r1_bf, ws_u + W_R2, I_t, ihat, scal);
}